// Round 1
// 166.576 us; speedup vs baseline: 1.1606x; 1.1606x over previous
//
#include <hip/hip_runtime.h>
#include <math.h>
#include <stdint.h>

// Problem constants (fixed by setup_inputs)
#define E_EDGES 16384
#define H_DIM   256
#define S_SEEDS 32
#define NHEADS  8
#define HDIM    32
#define BGRAPHS 16
#define EPG     1024
#define N2      512       // v (256) | scores (256)
#define RSQRT_HD 0.17677669529663687f

typedef __attribute__((ext_vector_type(8))) short bf16x8;   // 8 bf16 (4 VGPRs)
typedef __attribute__((ext_vector_type(4))) float f32x4;

__device__ inline unsigned short f2bf(float x) {            // round-to-nearest-even
    unsigned u = __float_as_uint(x);
    u += 0x7fff + ((u >> 16) & 1);
    return (unsigned short)(u >> 16);
}
__device__ inline float bf2f(unsigned int h) {
    return __uint_as_float((h & 0xffffu) << 16);
}

// ---------------- K1: WcT[n][k] bf16, n<256: Wv col, n>=256: folded q@Wk score col
// q computed cooperatively in-block (k_q kernel eliminated)
__global__ __launch_bounds__(256) void k_wc(const float* __restrict__ Wv,
                                            const float* __restrict__ Wk,
                                            const float* __restrict__ Wq,
                                            const float* __restrict__ seed,
                                            unsigned short* __restrict__ WcT) {
    int j = blockIdx.x;          // 0..511 output row (n), block-uniform
    int i = threadIdx.x;         // 0..255 (k index)
    float val;
    if (j < H_DIM) {
        val = Wv[i * H_DIM + j];
    } else {
        int c = j - H_DIM;
        int h = c >> 5, s = c & 31;
        __shared__ float qp[8][33];
        __shared__ float qrow[HDIM];
        // cooperative q-row: qrow[d] = sum_i seed[s,i] * Wq[i, h*32+d]
        int d = i & 31, g = i >> 5;
        const float* wq = &Wq[(g * 32) * H_DIM + h * HDIM + d];
        const float* sd = &seed[s * H_DIM + g * 32];
        float p = 0.f;
        #pragma unroll
        for (int ii = 0; ii < 32; ++ii)
            p = fmaf(sd[ii], wq[(size_t)ii * H_DIM], p);
        qp[g][d] = p;
        __syncthreads();
        if (i < HDIM) {
            float qv = 0.f;
            #pragma unroll
            for (int g2 = 0; g2 < 8; ++g2) qv += qp[g2][i];
            qrow[i] = qv;
        }
        __syncthreads();
        const float* wk = &Wk[i * H_DIM + h * HDIM];
        float acc = 0.f;
        #pragma unroll
        for (int dd = 0; dd < HDIM; dd += 4) {
            float4 w = *(const float4*)&wk[dd];
            float4 qq = *(const float4*)&qrow[dd];
            acc = fmaf(w.x, qq.x, acc); acc = fmaf(w.y, qq.y, acc);
            acc = fmaf(w.z, qq.z, acc); acc = fmaf(w.w, qq.w, acc);
        }
        val = acc * RSQRT_HD;
    }
    WcT[j * H_DIM + i] = f2bf(val);
}

// ---------------- K2: A fp32 -> bf16 ----------------
__global__ __launch_bounds__(256) void k_convA(const float* __restrict__ A,
                                               unsigned short* __restrict__ Abf) {
    size_t idx = (size_t)blockIdx.x * 256 + threadIdx.x;   // one per 8 floats
    const float4* src = (const float4*)A;
    float4 a = src[idx * 2], b = src[idx * 2 + 1];
    uint4 o;
    o.x = (unsigned)f2bf(a.x) | ((unsigned)f2bf(a.y) << 16);
    o.y = (unsigned)f2bf(a.z) | ((unsigned)f2bf(a.w) << 16);
    o.z = (unsigned)f2bf(b.x) | ((unsigned)f2bf(b.y) << 16);
    o.w = (unsigned)f2bf(b.z) | ((unsigned)f2bf(b.w) << 16);
    ((uint4*)Abf)[idx] = o;
}

// ---------------- K3: C[E,512] bf16 = Abf[E,256] @ WcT[512,256]^T via MFMA
// Score blocks (n0>=256) also emit per-128-edge-chunk softmax partials
// (col-max, col-expsum) from the accumulators -> k_smax eliminated.
#define BKP 40   // padded LDS k-stride (bf16 elems)
__global__ __launch_bounds__(256) void k_gemm(const unsigned short* __restrict__ Abf,
                                              const unsigned short* __restrict__ WcT,
                                              unsigned short* __restrict__ C,
                                              float* __restrict__ pmax,
                                              float* __restrict__ psum) {
    __shared__ unsigned short As[128][BKP];
    __shared__ unsigned short Bs[128][BKP];
    __shared__ float smx[2][128];
    __shared__ float ssm[2][128];
    int tid = threadIdx.x;
    int e0 = blockIdx.x * 128, n0 = blockIdx.y * 128;
    int w = tid >> 6, lane = tid & 63;
    int wm = (w >> 1) * 64, wn = (w & 1) * 64;
    int lr = lane & 15, kg = lane >> 4;          // frag row/col + k-group
    int srow = tid >> 1;                          // staging row 0..127
    int scol = (tid & 1) * 16;                    // element offset 0 or 16
    f32x4 acc[4][4] = {};
    for (int k0 = 0; k0 < H_DIM; k0 += 32) {
        // full 128x32 u16 tile: each thread loads 2 uint4 (16 u16) per matrix
        const unsigned short* ap = &Abf[(size_t)(e0 + srow) * H_DIM + k0 + scol];
        const unsigned short* bp = &WcT[(size_t)(n0 + srow) * H_DIM + k0 + scol];
        uint4 av0 = *(const uint4*)(ap);
        uint4 av1 = *(const uint4*)(ap + 8);
        uint4 bv0 = *(const uint4*)(bp);
        uint4 bv1 = *(const uint4*)(bp + 8);
        __syncthreads();                          // prior iter's frag reads done
        *(uint4*)&As[srow][scol]     = av0;
        *(uint4*)&As[srow][scol + 8] = av1;
        *(uint4*)&Bs[srow][scol]     = bv0;
        *(uint4*)&Bs[srow][scol + 8] = bv1;
        __syncthreads();
        bf16x8 af[4], bfv[4];
        #pragma unroll
        for (int mi = 0; mi < 4; ++mi)
            af[mi] = *(const bf16x8*)&As[wm + mi * 16 + lr][kg * 8];
        #pragma unroll
        for (int ni = 0; ni < 4; ++ni)
            bfv[ni] = *(const bf16x8*)&Bs[wn + ni * 16 + lr][kg * 8];
        #pragma unroll
        for (int mi = 0; mi < 4; ++mi)
            #pragma unroll
            for (int ni = 0; ni < 4; ++ni)
                acc[mi][ni] = __builtin_amdgcn_mfma_f32_16x16x32_bf16(af[mi], bfv[ni], acc[mi][ni], 0, 0, 0);
    }
    if (n0 >= H_DIM) {
        // round accs to bf16 first so partials are bit-consistent with the
        // bf16 C values k_wsum reads back (numerator/denominator must match).
        #pragma unroll
        for (int mi = 0; mi < 4; ++mi)
            #pragma unroll
            for (int ni = 0; ni < 4; ++ni)
                #pragma unroll
                for (int r = 0; r < 4; ++r)
                    acc[mi][ni][r] = bf2f(f2bf(acc[mi][ni][r]));
        // per-column max over the 128 rows of this e-chunk
        float tmax[4];
        #pragma unroll
        for (int ni = 0; ni < 4; ++ni) {
            float m = -1e30f;
            #pragma unroll
            for (int mi = 0; mi < 4; ++mi)
                #pragma unroll
                for (int r = 0; r < 4; ++r) m = fmaxf(m, acc[mi][ni][r]);
            m = fmaxf(m, __shfl_xor(m, 16, 64));   // reduce over kg (rows)
            m = fmaxf(m, __shfl_xor(m, 32, 64));
            tmax[ni] = m;
        }
        if (kg == 0) {
            #pragma unroll
            for (int ni = 0; ni < 4; ++ni) smx[w >> 1][wn + ni * 16 + lr] = tmax[ni];
        }
        __syncthreads();
        float csum[4];
        #pragma unroll
        for (int ni = 0; ni < 4; ++ni) {
            int col = wn + ni * 16 + lr;
            float m = fmaxf(smx[0][col], smx[1][col]);
            float s = 0.f;
            #pragma unroll
            for (int mi = 0; mi < 4; ++mi)
                #pragma unroll
                for (int r = 0; r < 4; ++r) s += __expf(acc[mi][ni][r] - m);
            s += __shfl_xor(s, 16, 64);
            s += __shfl_xor(s, 32, 64);
            csum[ni] = s;
        }
        if (kg == 0) {
            #pragma unroll
            for (int ni = 0; ni < 4; ++ni) ssm[w >> 1][wn + ni * 16 + lr] = csum[ni];
        }
        __syncthreads();
        if (tid < 128) {
            float m = fmaxf(smx[0][tid], smx[1][tid]);
            float s = ssm[0][tid] + ssm[1][tid];
            int gcol = (n0 - H_DIM) + tid;         // 0..255 score col
            pmax[(size_t)blockIdx.x * H_DIM + gcol] = m;
            psum[(size_t)blockIdx.x * H_DIM + gcol] = s;
        }
    }
    // C/D layout: col = lane&15, row = (lane>>4)*4 + reg  [m89-verified]
    #pragma unroll
    for (int mi = 0; mi < 4; ++mi)
        #pragma unroll
        for (int ni = 0; ni < 4; ++ni)
            #pragma unroll
            for (int r = 0; r < 4; ++r) {
                int e = e0 + wm + mi * 16 + kg * 4 + r;
                int n = n0 + wn + ni * 16 + lr;
                C[(size_t)e * N2 + n] = f2bf(acc[mi][ni][r]);
            }
}

// ---------------- K4: weighted-V over (b, h, 128-edge chunk); softmax combine inlined
__global__ __launch_bounds__(256) void k_wsum(const unsigned short* __restrict__ C,
                                              const float* __restrict__ pmax,
                                              const float* __restrict__ psum,
                                              float* __restrict__ patt) {
    int b = blockIdx.x, h = blockIdx.y, eq = blockIdx.z;   // 16 x 8 x 8
    int t = threadIdx.x;
    int s = t & 31, dg = t >> 5;
    __shared__ float pbuf[128][33];
    __shared__ float ml[32], il[32];
    if (t < 32) {                                  // inline k_smax_fin (redundant x8)
        int col = h * 32 + t;
        float m = -1e30f;
        #pragma unroll
        for (int j = 0; j < 8; ++j)
            m = fmaxf(m, pmax[(size_t)(b * 8 + j) * H_DIM + col]);
        float sm = 0.f;
        #pragma unroll
        for (int j = 0; j < 8; ++j)
            sm += psum[(size_t)(b * 8 + j) * H_DIM + col] *
                  __expf(pmax[(size_t)(b * 8 + j) * H_DIM + col] - m);
        ml[t] = m; il[t] = 1.f / sm;
    }
    __syncthreads();
    int e0 = b * EPG + eq * 128;
    #pragma unroll
    for (int ii = 0; ii < 16; ++ii) {
        int el = dg + 8 * ii;
        float x = bf2f(C[(size_t)(e0 + el) * N2 + H_DIM + h * 32 + s]);
        pbuf[el][s] = __expf(x - ml[s]) * il[s];
    }
    __syncthreads();
    float a0 = 0.f, a1 = 0.f, a2 = 0.f, a3 = 0.f;
    for (int el = 0; el < 128; ++el) {
        uint2 vv = *(const uint2*)&C[(size_t)(e0 + el) * N2 + h * 32 + dg * 4];
        float p = pbuf[el][s];
        a0 = fmaf(p, bf2f(vv.x), a0);
        a1 = fmaf(p, bf2f(vv.x >> 16), a1);
        a2 = fmaf(p, bf2f(vv.y), a2);
        a3 = fmaf(p, bf2f(vv.y >> 16), a3);
    }
    float4 o = {a0, a1, a2, a3};
    *(float4*)&patt[(size_t)((eq * 16 + b) * 32 + s) * H_DIM + h * 32 + dg * 4] = o;
}

// ---------------- block reduction helper (256 threads = 4 waves) ----------------
__device__ inline float block_sum256(float v, float* red4) {
    for (int o = 32; o > 0; o >>= 1) v += __shfl_xor(v, o, 64);
    int wid = threadIdx.x >> 6;
    if ((threadIdx.x & 63) == 0) red4[wid] = v;
    __syncthreads();
    float r = red4[0] + red4[1] + red4[2] + red4[3];
    __syncthreads();
    return r;
}

// ---------------- K5: y = LN(seed + att @ Wo + bo), 4 rows/block
// att assembled inline from the 8 patt partials (k_att_red eliminated)
__global__ __launch_bounds__(256) void k_proj_ln(const float* __restrict__ patt,
                                                 const float* __restrict__ seed,
                                                 const float* __restrict__ Wo,
                                                 const float* __restrict__ bo,
                                                 const float* __restrict__ ln_g,
                                                 const float* __restrict__ ln_b,
                                                 float* __restrict__ Y) {
    int bs0 = blockIdx.x * 4;             // 128 blocks x 4 (b,s) rows
    int c = threadIdx.x;
    __shared__ float arow[4][H_DIM];
    __shared__ float red4[4];
    #pragma unroll
    for (int r = 0; r < 4; ++r) {
        int bs = bs0 + r;
        int b = bs >> 5, s = bs & 31;
        float a = 0.f;
        #pragma unroll
        for (int eq = 0; eq < 8; ++eq)
            a += patt[(size_t)((eq * 16 + b) * 32 + s) * H_DIM + c];
        arow[r][c] = a;
    }
    __syncthreads();
    float acc[4];
    float b0 = bo[c];
    #pragma unroll
    for (int r = 0; r < 4; ++r) acc[r] = b0;
    for (int i = 0; i < H_DIM; i += 4) {
        float4 a0 = *(const float4*)&arow[0][i];
        float4 a1 = *(const float4*)&arow[1][i];
        float4 a2 = *(const float4*)&arow[2][i];
        float4 a3 = *(const float4*)&arow[3][i];
        float w0 = Wo[(i + 0) * H_DIM + c], w1 = Wo[(i + 1) * H_DIM + c];
        float w2 = Wo[(i + 2) * H_DIM + c], w3 = Wo[(i + 3) * H_DIM + c];
        acc[0] = fmaf(a0.x, w0, acc[0]); acc[0] = fmaf(a0.y, w1, acc[0]);
        acc[0] = fmaf(a0.z, w2, acc[0]); acc[0] = fmaf(a0.w, w3, acc[0]);
        acc[1] = fmaf(a1.x, w0, acc[1]); acc[1] = fmaf(a1.y, w1, acc[1]);
        acc[1] = fmaf(a1.z, w2, acc[1]); acc[1] = fmaf(a1.w, w3, acc[1]);
        acc[2] = fmaf(a2.x, w0, acc[2]); acc[2] = fmaf(a2.y, w1, acc[2]);
        acc[2] = fmaf(a2.z, w2, acc[2]); acc[2] = fmaf(a2.w, w3, acc[2]);
        acc[3] = fmaf(a3.x, w0, acc[3]); acc[3] = fmaf(a3.y, w1, acc[3]);
        acc[3] = fmaf(a3.z, w2, acc[3]); acc[3] = fmaf(a3.w, w3, acc[3]);
    }
    float g = ln_g[c], be = ln_b[c];
    #pragma unroll
    for (int r = 0; r < 4; ++r) {
        int bs = bs0 + r;
        float y = seed[(bs & 31) * H_DIM + c] + acc[r];
        float mu = block_sum256(y, red4) * (1.f / 256.f);
        float d = y - mu;
        float var = block_sum256(d * d, red4) * (1.f / 256.f);
        Y[(size_t)bs * H_DIM + c] = d * rsqrtf(var + 1e-5f) * g + be;
    }
}

// ---------------- K6: MLP1 partials, W1 read exactly once ----------------
__global__ __launch_bounds__(256) void k_mlp1(const float* __restrict__ Y,
                                              const float* __restrict__ W1,
                                              float* __restrict__ part) {
    int ch = blockIdx.x;          // 128 chunks x 64 rows of W1
    int c = threadIdx.x;
    int i0 = ch * 64;
    __shared__ float fbuf[16][64];
    #pragma unroll
    for (int it = 0; it < 4; ++it) {
        int li = it * 256 + c;
        fbuf[li >> 6][li & 63] = Y[(size_t)(li >> 6) * 8192 + i0 + (li & 63)];
    }
    __syncthreads();
    float acc[16];
    #pragma unroll
    for (int b = 0; b < 16; ++b) acc[b] = 0.f;
    for (int ii = 0; ii < 64; ++ii) {
        float w = W1[(size_t)(i0 + ii) * H_DIM + c];
        #pragma unroll
        for (int b = 0; b < 16; ++b) acc[b] = fmaf(fbuf[b][ii], w, acc[b]);
    }
    #pragma unroll
    for (int b = 0; b < 16; ++b)
        part[((size_t)b * 128 + ch) * H_DIM + c] = acc[b];
}

// ---------------- K7: reduce + SiLU + @W2 + b2 ----------------
__global__ __launch_bounds__(256) void k_mlp2(const float* __restrict__ part,
                                              const float* __restrict__ b1,
                                              const float* __restrict__ W2,
                                              const float* __restrict__ b2,
                                              float* __restrict__ out) {
    int b = blockIdx.x;
    int c = threadIdx.x;
    float s = b1[c];
    const float* pb = &part[(size_t)b * 128 * H_DIM + c];
    #pragma unroll 4
    for (int ch = 0; ch < 128; ++ch) s += pb[(size_t)ch * H_DIM];
    float h1 = s / (1.f + __expf(-s));
    __shared__ float hrow[H_DIM];
    hrow[c] = h1;
    __syncthreads();
    float acc = b2[c];
    for (int j = 0; j < H_DIM; j += 4) {
        float4 hq = *(const float4*)&hrow[j];
        acc = fmaf(hq.x, W2[(j + 0) * H_DIM + c], acc);
        acc = fmaf(hq.y, W2[(j + 1) * H_DIM + c], acc);
        acc = fmaf(hq.z, W2[(j + 2) * H_DIM + c], acc);
        acc = fmaf(hq.w, W2[(j + 3) * H_DIM + c], acc);
    }
    out[(size_t)b * H_DIM + c] = acc;
}

extern "C" void kernel_launch(void* const* d_in, const int* in_sizes, int n_in,
                              void* d_out, int out_size, void* d_ws, size_t ws_size,
                              hipStream_t stream) {
    const float* edge_features = (const float*)d_in[0];
    const float* seed = (const float*)d_in[3];
    const float* Wq   = (const float*)d_in[4];
    const float* Wk   = (const float*)d_in[5];
    const float* Wv   = (const float*)d_in[6];
    const float* Wo   = (const float*)d_in[7];
    const float* bo   = (const float*)d_in[8];
    const float* ln_g = (const float*)d_in[9];
    const float* ln_b = (const float*)d_in[10];
    const float* W1   = (const float*)d_in[11];
    const float* b1   = (const float*)d_in[12];
    const float* W2   = (const float*)d_in[13];
    const float* b2   = (const float*)d_in[14];
    float* out = (float*)d_out;

    // Workspace layout (floats). Abf aliases the post-GEMM region (dead after k_gemm).
    float* ws = (float*)d_ws;
    unsigned short* WcT  = (unsigned short*)ws;                   // 512*256 u16 (65536 f)
    unsigned short* C    = WcT + 512 * H_DIM;                     // 16384*512 u16 (4.19M f)
    float*          post = (float*)(C + (size_t)E_EDGES * N2);
    unsigned short* Abf  = (unsigned short*)post;                 // 16384*256 u16 (2.10M f)
    float* pmax = post;                                           // 128*256 = 32768
    float* psum = pmax + 32768;                                   // 32768
    float* patt = psum + 32768;                                   // 8*16*32*256 = 1048576
    float* Y    = patt + 1048576;                                 // 131072
    float* part = Y + 131072;                                     // 16*128*256 = 524288
    // union = 1.77M floats < 2.10M (Abf) -> total ws ~= 25.4 MB

    k_wc       <<<N2, 256, 0, stream>>>(Wv, Wk, Wq, seed, WcT);
    k_convA    <<<E_EDGES * H_DIM / (256 * 8), 256, 0, stream>>>(edge_features, Abf);
    k_gemm     <<<dim3(E_EDGES / 128, N2 / 128), 256, 0, stream>>>(Abf, WcT, C, pmax, psum);
    k_wsum     <<<dim3(BGRAPHS, NHEADS, 8), 256, 0, stream>>>(C, pmax, psum, patt);
    k_proj_ln  <<<BGRAPHS * S_SEEDS / 4, 256, 0, stream>>>(patt, seed, Wo, bo, ln_g, ln_b, Y);
    k_mlp1     <<<128, 256, 0, stream>>>(Y, W1, part);
    k_mlp2     <<<BGRAPHS, 256, 0, stream>>>(part, b1, W2, b2, out);
}

// Round 2
// 158.820 us; speedup vs baseline: 1.2172x; 1.0488x over previous
//
#include <hip/hip_runtime.h>
#include <math.h>
#include <stdint.h>

// Problem constants (fixed by setup_inputs)
#define E_EDGES 16384
#define H_DIM   256
#define S_SEEDS 32
#define NHEADS  8
#define HDIM    32
#define BGRAPHS 16
#define EPG     1024
#define N2      512       // v (256) | scores (256)
#define RSQRT_HD 0.17677669529663687f

typedef __attribute__((ext_vector_type(8))) short bf16x8;   // 8 bf16 (4 VGPRs)
typedef __attribute__((ext_vector_type(4))) float f32x4;

__device__ inline unsigned short f2bf(float x) {            // round-to-nearest-even
    unsigned u = __float_as_uint(x);
    u += 0x7fff + ((u >> 16) & 1);
    return (unsigned short)(u >> 16);
}
__device__ inline float bf2f(unsigned int h) {
    return __uint_as_float((h & 0xffffu) << 16);
}
__device__ inline unsigned pack2(float a, float b) {
    return (unsigned)f2bf(a) | ((unsigned)f2bf(b) << 16);
}

// ---------------- K1: WcT[n][k] bf16, n<256: Wv col, n>=256: folded q@Wk score col
__global__ __launch_bounds__(256) void k_wc(const float* __restrict__ Wv,
                                            const float* __restrict__ Wk,
                                            const float* __restrict__ Wq,
                                            const float* __restrict__ seed,
                                            unsigned short* __restrict__ WcT) {
    int j = blockIdx.x;          // 0..511 output row (n), block-uniform
    int i = threadIdx.x;         // 0..255 (k index)
    float val;
    if (j < H_DIM) {
        val = Wv[i * H_DIM + j];
    } else {
        int c = j - H_DIM;
        int h = c >> 5, s = c & 31;
        __shared__ float qp[8][33];
        __shared__ float qrow[HDIM];
        // cooperative q-row: qrow[d] = sum_i seed[s,i] * Wq[i, h*32+d]
        int d = i & 31, g = i >> 5;
        const float* wq = &Wq[(g * 32) * H_DIM + h * HDIM + d];
        const float* sd = &seed[s * H_DIM + g * 32];
        float p = 0.f;
        #pragma unroll
        for (int ii = 0; ii < 32; ++ii)
            p = fmaf(sd[ii], wq[(size_t)ii * H_DIM], p);
        qp[g][d] = p;
        __syncthreads();
        if (i < HDIM) {
            float qv = 0.f;
            #pragma unroll
            for (int g2 = 0; g2 < 8; ++g2) qv += qp[g2][i];
            qrow[i] = qv;
        }
        __syncthreads();
        const float* wk = &Wk[i * H_DIM + h * HDIM];
        float acc = 0.f;
        #pragma unroll
        for (int dd = 0; dd < HDIM; dd += 4) {
            float4 w = *(const float4*)&wk[dd];
            float4 qq = *(const float4*)&qrow[dd];
            acc = fmaf(w.x, qq.x, acc); acc = fmaf(w.y, qq.y, acc);
            acc = fmaf(w.z, qq.z, acc); acc = fmaf(w.w, qq.w, acc);
        }
        val = acc * RSQRT_HD;
    }
    WcT[j * H_DIM + i] = f2bf(val);
}

// ---------------- K2: C[E,512] bf16 = bf16(A_fp32)[E,256] @ WcT[512,256]^T via MFMA
// A conversion fused into staging (k_convA eliminated).
// Score blocks (n0>=256) also emit per-128-edge-chunk softmax partials.
#define BKP 40   // padded LDS k-stride (bf16 elems)
__global__ __launch_bounds__(256) void k_gemm(const float* __restrict__ A,
                                              const unsigned short* __restrict__ WcT,
                                              unsigned short* __restrict__ C,
                                              float* __restrict__ pmax,
                                              float* __restrict__ psum) {
    __shared__ unsigned short As[128][BKP];
    __shared__ unsigned short Bs[128][BKP];
    __shared__ float smx[2][128];
    __shared__ float ssm[2][128];
    int tid = threadIdx.x;
    int e0 = blockIdx.x * 128, n0 = blockIdx.y * 128;
    int w = tid >> 6, lane = tid & 63;
    int wm = (w >> 1) * 64, wn = (w & 1) * 64;
    int lr = lane & 15, kg = lane >> 4;          // frag row/col + k-group
    int srow = tid >> 1;                          // staging row 0..127
    int scol = (tid & 1) * 16;                    // element offset 0 or 16
    f32x4 acc[4][4] = {};
    for (int k0 = 0; k0 < H_DIM; k0 += 32) {
        // A: 16 fp32 per thread, converted to bf16 in-register
        const float* ap = &A[(size_t)(e0 + srow) * H_DIM + k0 + scol];
        float4 a0 = *(const float4*)(ap);
        float4 a1 = *(const float4*)(ap + 4);
        float4 a2 = *(const float4*)(ap + 8);
        float4 a3 = *(const float4*)(ap + 12);
        const unsigned short* bp = &WcT[(size_t)(n0 + srow) * H_DIM + k0 + scol];
        uint4 bv0 = *(const uint4*)(bp);
        uint4 bv1 = *(const uint4*)(bp + 8);
        uint4 av0, av1;
        av0.x = pack2(a0.x, a0.y); av0.y = pack2(a0.z, a0.w);
        av0.z = pack2(a1.x, a1.y); av0.w = pack2(a1.z, a1.w);
        av1.x = pack2(a2.x, a2.y); av1.y = pack2(a2.z, a2.w);
        av1.z = pack2(a3.x, a3.y); av1.w = pack2(a3.z, a3.w);
        __syncthreads();                          // prior iter's frag reads done
        *(uint4*)&As[srow][scol]     = av0;
        *(uint4*)&As[srow][scol + 8] = av1;
        *(uint4*)&Bs[srow][scol]     = bv0;
        *(uint4*)&Bs[srow][scol + 8] = bv1;
        __syncthreads();
        bf16x8 af[4], bfv[4];
        #pragma unroll
        for (int mi = 0; mi < 4; ++mi)
            af[mi] = *(const bf16x8*)&As[wm + mi * 16 + lr][kg * 8];
        #pragma unroll
        for (int ni = 0; ni < 4; ++ni)
            bfv[ni] = *(const bf16x8*)&Bs[wn + ni * 16 + lr][kg * 8];
        #pragma unroll
        for (int mi = 0; mi < 4; ++mi)
            #pragma unroll
            for (int ni = 0; ni < 4; ++ni)
                acc[mi][ni] = __builtin_amdgcn_mfma_f32_16x16x32_bf16(af[mi], bfv[ni], acc[mi][ni], 0, 0, 0);
    }
    if (n0 >= H_DIM) {
        // round accs to bf16 first so partials are bit-consistent with the
        // bf16 C values k_wsum reads back.
        #pragma unroll
        for (int mi = 0; mi < 4; ++mi)
            #pragma unroll
            for (int ni = 0; ni < 4; ++ni)
                #pragma unroll
                for (int r = 0; r < 4; ++r)
                    acc[mi][ni][r] = bf2f(f2bf(acc[mi][ni][r]));
        float tmax[4];
        #pragma unroll
        for (int ni = 0; ni < 4; ++ni) {
            float m = -1e30f;
            #pragma unroll
            for (int mi = 0; mi < 4; ++mi)
                #pragma unroll
                for (int r = 0; r < 4; ++r) m = fmaxf(m, acc[mi][ni][r]);
            m = fmaxf(m, __shfl_xor(m, 16, 64));   // reduce over kg (rows)
            m = fmaxf(m, __shfl_xor(m, 32, 64));
            tmax[ni] = m;
        }
        if (kg == 0) {
            #pragma unroll
            for (int ni = 0; ni < 4; ++ni) smx[w >> 1][wn + ni * 16 + lr] = tmax[ni];
        }
        __syncthreads();
        float csum[4];
        #pragma unroll
        for (int ni = 0; ni < 4; ++ni) {
            int col = wn + ni * 16 + lr;
            float m = fmaxf(smx[0][col], smx[1][col]);
            float sv = 0.f;
            #pragma unroll
            for (int mi = 0; mi < 4; ++mi)
                #pragma unroll
                for (int r = 0; r < 4; ++r) sv += __expf(acc[mi][ni][r] - m);
            sv += __shfl_xor(sv, 16, 64);
            sv += __shfl_xor(sv, 32, 64);
            csum[ni] = sv;
        }
        if (kg == 0) {
            #pragma unroll
            for (int ni = 0; ni < 4; ++ni) ssm[w >> 1][wn + ni * 16 + lr] = csum[ni];
        }
        __syncthreads();
        if (tid < 128) {
            float m = fmaxf(smx[0][tid], smx[1][tid]);
            float sv = ssm[0][tid] + ssm[1][tid];
            int gcol = (n0 - H_DIM) + tid;         // 0..255 score col
            pmax[(size_t)blockIdx.x * H_DIM + gcol] = m;
            psum[(size_t)blockIdx.x * H_DIM + gcol] = sv;
        }
    }
    // C/D layout: col = lane&15, row = (lane>>4)*4 + reg  [m89-verified]
    #pragma unroll
    for (int mi = 0; mi < 4; ++mi)
        #pragma unroll
        for (int ni = 0; ni < 4; ++ni)
            #pragma unroll
            for (int r = 0; r < 4; ++r) {
                int e = e0 + wm + mi * 16 + kg * 4 + r;
                int n = n0 + wn + ni * 16 + lr;
                C[(size_t)e * N2 + n] = f2bf(acc[mi][ni][r]);
            }
}

// ---------------- K3: weighted-V; LDS-staged score/V tiles; 2 chunks/block
#define VSP 40   // padded LDS stride (u16) for score/V tiles; 80 B, 16 B-aligned rows
__global__ __launch_bounds__(256) void k_wsum(const unsigned short* __restrict__ C,
                                              const float* __restrict__ pmax,
                                              const float* __restrict__ psum,
                                              float* __restrict__ patt) {
    int b = blockIdx.x, h = blockIdx.y, pp = blockIdx.z;   // 16 x 8 x 4
    int t = threadIdx.x;
    int s = t & 31, dg = t >> 5;                // dg 0..7
    __shared__ unsigned short sbuf[128][VSP];
    __shared__ unsigned short vbuf[128][VSP];
    __shared__ float pbuf[128][33];
    __shared__ float ml[32], il[32];
    if (t < 32) {                               // inline global softmax combine
        int col = h * 32 + t;
        float m = -1e30f;
        #pragma unroll
        for (int j = 0; j < 8; ++j)
            m = fmaxf(m, pmax[(size_t)(b * 8 + j) * H_DIM + col]);
        float sm = 0.f;
        #pragma unroll
        for (int j = 0; j < 8; ++j)
            sm += psum[(size_t)(b * 8 + j) * H_DIM + col] *
                  __expf(pmax[(size_t)(b * 8 + j) * H_DIM + col] - m);
        ml[t] = m; il[t] = 1.f / sm;
    }
    int r = t >> 1, halfo = (t & 1) * 16;       // staging: row, u16 offset
    float a0 = 0.f, a1 = 0.f, a2 = 0.f, a3 = 0.f;
    for (int ch = 0; ch < 2; ++ch) {
        int e0 = b * EPG + (pp * 2 + ch) * 128;
        const unsigned short* crow = &C[(size_t)(e0 + r) * N2 + h * 32 + halfo];
        uint4 sv0 = *(const uint4*)(crow + H_DIM);
        uint4 sv1 = *(const uint4*)(crow + H_DIM + 8);
        uint4 vv0 = *(const uint4*)(crow);
        uint4 vv1 = *(const uint4*)(crow + 8);
        __syncthreads();                        // prev-iter LDS reads done (+ml ready)
        *(uint4*)&sbuf[r][halfo]     = sv0;
        *(uint4*)&sbuf[r][halfo + 8] = sv1;
        *(uint4*)&vbuf[r][halfo]     = vv0;
        *(uint4*)&vbuf[r][halfo + 8] = vv1;
        __syncthreads();
        #pragma unroll
        for (int ii = 0; ii < 16; ++ii) {       // exp weights (shared across dg)
            int el = dg + 8 * ii;
            float x = bf2f(sbuf[el][s]);
            pbuf[el][s] = __expf(x - ml[s]) * il[s];
        }
        __syncthreads();
        #pragma unroll 16
        for (int el = 0; el < 128; ++el) {
            float p = pbuf[el][s];
            uint2 vv = *(const uint2*)&vbuf[el][dg * 4];
            a0 = fmaf(p, bf2f(vv.x), a0);
            a1 = fmaf(p, bf2f(vv.x >> 16), a1);
            a2 = fmaf(p, bf2f(vv.y), a2);
            a3 = fmaf(p, bf2f(vv.y >> 16), a3);
        }
    }
    float4 o = {a0, a1, a2, a3};
    *(float4*)&patt[(size_t)((pp * 16 + b) * 32 + s) * H_DIM + h * 32 + dg * 4] = o;
}

// ---------------- block reduction helper (256 threads = 4 waves) ----------------
__device__ inline float block_sum256(float v, float* red4) {
    for (int o = 32; o > 0; o >>= 1) v += __shfl_xor(v, o, 64);
    int wid = threadIdx.x >> 6;
    if ((threadIdx.x & 63) == 0) red4[wid] = v;
    __syncthreads();
    float r = red4[0] + red4[1] + red4[2] + red4[3];
    __syncthreads();
    return r;
}

// ---------------- K4: y = LN(seed + att @ Wo + bo), 4 rows/block
__global__ __launch_bounds__(256) void k_proj_ln(const float* __restrict__ patt,
                                                 const float* __restrict__ seed,
                                                 const float* __restrict__ Wo,
                                                 const float* __restrict__ bo,
                                                 const float* __restrict__ ln_g,
                                                 const float* __restrict__ ln_b,
                                                 float* __restrict__ Y) {
    int bs0 = blockIdx.x * 4;             // 128 blocks x 4 (b,s) rows
    int c = threadIdx.x;
    __shared__ float arow[4][H_DIM];
    __shared__ float red4[4];
    #pragma unroll
    for (int r = 0; r < 4; ++r) {
        int bs = bs0 + r;
        int b = bs >> 5, s = bs & 31;
        float a = 0.f;
        #pragma unroll
        for (int eq = 0; eq < 4; ++eq)
            a += patt[(size_t)((eq * 16 + b) * 32 + s) * H_DIM + c];
        arow[r][c] = a;
    }
    __syncthreads();
    float acc[4];
    float b0 = bo[c];
    #pragma unroll
    for (int r = 0; r < 4; ++r) acc[r] = b0;
    for (int i = 0; i < H_DIM; i += 4) {
        float4 a0 = *(const float4*)&arow[0][i];
        float4 a1 = *(const float4*)&arow[1][i];
        float4 a2 = *(const float4*)&arow[2][i];
        float4 a3 = *(const float4*)&arow[3][i];
        float w0 = Wo[(i + 0) * H_DIM + c], w1 = Wo[(i + 1) * H_DIM + c];
        float w2 = Wo[(i + 2) * H_DIM + c], w3 = Wo[(i + 3) * H_DIM + c];
        acc[0] = fmaf(a0.x, w0, acc[0]); acc[0] = fmaf(a0.y, w1, acc[0]);
        acc[0] = fmaf(a0.z, w2, acc[0]); acc[0] = fmaf(a0.w, w3, acc[0]);
        acc[1] = fmaf(a1.x, w0, acc[1]); acc[1] = fmaf(a1.y, w1, acc[1]);
        acc[1] = fmaf(a1.z, w2, acc[1]); acc[1] = fmaf(a1.w, w3, acc[1]);
        acc[2] = fmaf(a2.x, w0, acc[2]); acc[2] = fmaf(a2.y, w1, acc[2]);
        acc[2] = fmaf(a2.z, w2, acc[2]); acc[2] = fmaf(a2.w, w3, acc[2]);
        acc[3] = fmaf(a3.x, w0, acc[3]); acc[3] = fmaf(a3.y, w1, acc[3]);
        acc[3] = fmaf(a3.z, w2, acc[3]); acc[3] = fmaf(a3.w, w3, acc[3]);
    }
    float g = ln_g[c], be = ln_b[c];
    #pragma unroll
    for (int r = 0; r < 4; ++r) {
        int bs = bs0 + r;
        float y = seed[(bs & 31) * H_DIM + c] + acc[r];
        float mu = block_sum256(y, red4) * (1.f / 256.f);
        float d = y - mu;
        float var = block_sum256(d * d, red4) * (1.f / 256.f);
        Y[(size_t)bs * H_DIM + c] = d * rsqrtf(var + 1e-5f) * g + be;
    }
}

// ---------------- K5: MLP1 partials, W1 read exactly once ----------------
__global__ __launch_bounds__(256) void k_mlp1(const float* __restrict__ Y,
                                              const float* __restrict__ W1,
                                              float* __restrict__ part) {
    int ch = blockIdx.x;          // 128 chunks x 64 rows of W1
    int c = threadIdx.x;
    int i0 = ch * 64;
    __shared__ float fbuf[16][64];
    #pragma unroll
    for (int it = 0; it < 4; ++it) {
        int li = it * 256 + c;
        fbuf[li >> 6][li & 63] = Y[(size_t)(li >> 6) * 8192 + i0 + (li & 63)];
    }
    __syncthreads();
    float acc[16];
    #pragma unroll
    for (int b = 0; b < 16; ++b) acc[b] = 0.f;
    for (int ii = 0; ii < 64; ++ii) {
        float w = W1[(size_t)(i0 + ii) * H_DIM + c];
        #pragma unroll
        for (int b = 0; b < 16; ++b) acc[b] = fmaf(fbuf[b][ii], w, acc[b]);
    }
    #pragma unroll
    for (int b = 0; b < 16; ++b)
        part[((size_t)b * 128 + ch) * H_DIM + c] = acc[b];
}

// ---------------- K6: reduce + SiLU + @W2 + b2 ----------------
__global__ __launch_bounds__(256) void k_mlp2(const float* __restrict__ part,
                                              const float* __restrict__ b1,
                                              const float* __restrict__ W2,
                                              const float* __restrict__ b2,
                                              float* __restrict__ out) {
    int b = blockIdx.x;
    int c = threadIdx.x;
    float s = b1[c];
    const float* pb = &part[(size_t)b * 128 * H_DIM + c];
    #pragma unroll 4
    for (int ch = 0; ch < 128; ++ch) s += pb[(size_t)ch * H_DIM];
    float h1 = s / (1.f + __expf(-s));
    __shared__ float hrow[H_DIM];
    hrow[c] = h1;
    __syncthreads();
    float acc = b2[c];
    for (int j = 0; j < H_DIM; j += 4) {
        float4 hq = *(const float4*)&hrow[j];
        acc = fmaf(hq.x, W2[(j + 0) * H_DIM + c], acc);
        acc = fmaf(hq.y, W2[(j + 1) * H_DIM + c], acc);
        acc = fmaf(hq.z, W2[(j + 2) * H_DIM + c], acc);
        acc = fmaf(hq.w, W2[(j + 3) * H_DIM + c], acc);
    }
    out[(size_t)b * H_DIM + c] = acc;
}

extern "C" void kernel_launch(void* const* d_in, const int* in_sizes, int n_in,
                              void* d_out, int out_size, void* d_ws, size_t ws_size,
                              hipStream_t stream) {
    const float* edge_features = (const float*)d_in[0];
    const float* seed = (const float*)d_in[3];
    const float* Wq   = (const float*)d_in[4];
    const float* Wk   = (const float*)d_in[5];
    const float* Wv   = (const float*)d_in[6];
    const float* Wo   = (const float*)d_in[7];
    const float* bo   = (const float*)d_in[8];
    const float* ln_g = (const float*)d_in[9];
    const float* ln_b = (const float*)d_in[10];
    const float* W1   = (const float*)d_in[11];
    const float* b1   = (const float*)d_in[12];
    const float* W2   = (const float*)d_in[13];
    const float* b2   = (const float*)d_in[14];
    float* out = (float*)d_out;

    // Workspace layout (floats). No aliasing needed (Abf eliminated).
    float* ws = (float*)d_ws;
    unsigned short* WcT  = (unsigned short*)ws;                   // 512*256 u16 (65536 f)
    unsigned short* C    = WcT + 512 * H_DIM;                     // 16384*512 u16 (4.19M f)
    float* pmax = (float*)(C + (size_t)E_EDGES * N2);             // 128*256 = 32768
    float* psum = pmax + 32768;                                   // 32768
    float* patt = psum + 32768;                                   // 4*16*32*256 = 524288
    float* Y    = patt + 524288;                                  // 131072
    float* part = Y + 131072;                                     // 16*128*256 = 524288
    // total ~= 5.5M floats ~= 22 MB

    k_wc       <<<N2, 256, 0, stream>>>(Wv, Wk, Wq, seed, WcT);
    k_gemm     <<<dim3(E_EDGES / 128, N2 / 128), 256, 0, stream>>>(edge_features, WcT, C, pmax, psum);
    k_wsum     <<<dim3(BGRAPHS, NHEADS, 4), 256, 0, stream>>>(C, pmax, psum, patt);
    k_proj_ln  <<<BGRAPHS * S_SEEDS / 4, 256, 0, stream>>>(patt, seed, Wo, bo, ln_g, ln_b, Y);
    k_mlp1     <<<128, 256, 0, stream>>>(Y, W1, part);
    k_mlp2     <<<BGRAPHS, 256, 0, stream>>>(part, b1, W2, b2, out);
}

// Round 3
// 152.798 us; speedup vs baseline: 1.2652x; 1.0394x over previous
//
#include <hip/hip_runtime.h>
#include <math.h>
#include <stdint.h>

// Problem constants (fixed by setup_inputs)
#define E_EDGES 16384
#define H_DIM   256
#define S_SEEDS 32
#define NHEADS  8
#define HDIM    32
#define BGRAPHS 16
#define EPG     1024
#define NCHUNK  256       // 64-edge chunks
#define CPG     16        // chunks per graph
#define RSQRT_HD 0.17677669529663687f

typedef __attribute__((ext_vector_type(8))) short bf16x8;   // 8 bf16 (4 VGPRs)
typedef __attribute__((ext_vector_type(4))) float f32x4;

__device__ inline unsigned short f2bf(float x) {            // round-to-nearest-even
    unsigned u = __float_as_uint(x);
    u += 0x7fff + ((u >> 16) & 1);
    return (unsigned short)(u >> 16);
}
__device__ inline float bf2f(unsigned int h) {
    return __uint_as_float((h & 0xffffu) << 16);
}
__device__ inline unsigned pack2(float a, float b) {
    return (unsigned)f2bf(a) | ((unsigned)f2bf(b) << 16);
}

// ---------------- K1: WcT[n][k] bf16, n<256: Wv col, n>=256: folded q@Wk score col
__global__ __launch_bounds__(256) void k_wc(const float* __restrict__ Wv,
                                            const float* __restrict__ Wk,
                                            const float* __restrict__ Wq,
                                            const float* __restrict__ seed,
                                            unsigned short* __restrict__ WcT) {
    int j = blockIdx.x;          // 0..511 output row (n), block-uniform
    int i = threadIdx.x;         // 0..255 (k index)
    float val;
    if (j < H_DIM) {
        val = Wv[i * H_DIM + j];
    } else {
        int c = j - H_DIM;
        int h = c >> 5, s = c & 31;
        __shared__ float qp[8][33];
        __shared__ float qrow[HDIM];
        int d = i & 31, g = i >> 5;
        const float* wq = &Wq[(g * 32) * H_DIM + h * HDIM + d];
        const float* sd = &seed[s * H_DIM + g * 32];
        float p = 0.f;
        #pragma unroll
        for (int ii = 0; ii < 32; ++ii)
            p = fmaf(sd[ii], wq[(size_t)ii * H_DIM], p);
        qp[g][d] = p;
        __syncthreads();
        if (i < HDIM) {
            float qv = 0.f;
            #pragma unroll
            for (int g2 = 0; g2 < 8; ++g2) qv += qp[g2][i];
            qrow[i] = qv;
        }
        __syncthreads();
        const float* wk = &Wk[i * H_DIM + h * HDIM];
        float acc = 0.f;
        #pragma unroll
        for (int dd = 0; dd < HDIM; dd += 4) {
            float4 w = *(const float4*)&wk[dd];
            float4 qq = *(const float4*)&qrow[dd];
            acc = fmaf(w.x, qq.x, acc); acc = fmaf(w.y, qq.y, acc);
            acc = fmaf(w.z, qq.z, acc); acc = fmaf(w.w, qq.w, acc);
        }
        val = acc * RSQRT_HD;
    }
    WcT[j * H_DIM + i] = f2bf(val);
}

// ---------------- K2: fused attention per 64-edge chunk ----------------
// Per block: A-tile (64x256) resident in LDS (bf16); stream WcT n-tiles
// (V0,V1,S0,S1) with reg-prefetched k-slices; V kept transposed in LDS;
// scores -> chunk softmax (fp32 scores, bf16 P) -> P^T @ V via 2nd MFMA.
// Outputs: outc[chunk][32][256] fp32 partial, mg/sg[chunk][256] partials.
__global__ __launch_bounds__(256) void k_attn(const float* __restrict__ A,
                                              const unsigned short* __restrict__ WcT,
                                              float* __restrict__ outc,
                                              float* __restrict__ mg,
                                              float* __restrict__ sg) {
    __shared__ unsigned short As[64][264];       // 33792 B, pad: row stride 528B
    __shared__ unsigned short Bs[2][128][40];    // 20480 B, dbuf k-slices
    __shared__ unsigned short Vt[256][72];       // 36864 B, V transposed [d][e]
    __shared__ unsigned short Pt[128][72];       // 18432 B, P transposed [col][e]
    __shared__ float smx[2][128];
    __shared__ float ssm[2][128];
    int tid = threadIdx.x;
    int chunk = blockIdx.x;
    int e0 = chunk * 64;
    int w = tid >> 6, lane = tid & 63;
    int lr = lane & 15, kg = lane >> 4;
    int wm = (w & 1) * 32, wn = (w >> 1) * 64;   // wave sub-tile 32x64 of 64x128

    // ---- A prologue: 64x256 fp32 -> bf16 LDS ----
    {
        int r = tid >> 2, sg4 = tid & 3;
        const float* ap = &A[(size_t)(e0 + r) * H_DIM + sg4 * 64];
        #pragma unroll
        for (int i = 0; i < 8; ++i) {
            float4 x = *(const float4*)&ap[i * 8];
            float4 y = *(const float4*)&ap[i * 8 + 4];
            uint4 o;
            o.x = pack2(x.x, x.y); o.y = pack2(x.z, x.w);
            o.z = pack2(y.x, y.y); o.w = pack2(y.z, y.w);
            *(uint4*)&As[r][sg4 * 64 + i * 8] = o;
        }
    }
    int brow = tid >> 1, bhalf = (tid & 1) * 16;
    f32x4 acc2[2][2][2] = {};                    // [stile][ms][nd]
    uint4 pb0, pb1;
    {   // preload nt=0, k=0
        const unsigned short* bp = &WcT[(size_t)brow * H_DIM + bhalf];
        pb0 = *(const uint4*)bp; pb1 = *(const uint4*)(bp + 8);
    }
    #pragma unroll
    for (int nt = 0; nt < 4; ++nt) {
        f32x4 acc[2][4] = {};                    // [mi][ni]
        #pragma unroll
        for (int k = 0; k < 8; ++k) {
            *(uint4*)&Bs[k & 1][brow][bhalf]     = pb0;
            *(uint4*)&Bs[k & 1][brow][bhalf + 8] = pb1;
            __syncthreads();
            int nk = k + 1, nnt = nt;
            if (nk == 8) { nk = 0; nnt = nt + 1; }
            if (nnt < 4) {
                const unsigned short* bp =
                    &WcT[(size_t)(nnt * 128 + brow) * H_DIM + nk * 32 + bhalf];
                pb0 = *(const uint4*)bp; pb1 = *(const uint4*)(bp + 8);
            }
            bf16x8 af[2], bfv[4];
            #pragma unroll
            for (int mi = 0; mi < 2; ++mi)
                af[mi] = *(const bf16x8*)&As[wm + mi * 16 + lr][k * 32 + kg * 8];
            #pragma unroll
            for (int ni = 0; ni < 4; ++ni)
                bfv[ni] = *(const bf16x8*)&Bs[k & 1][wn + ni * 16 + lr][kg * 8];
            #pragma unroll
            for (int mi = 0; mi < 2; ++mi)
                #pragma unroll
                for (int ni = 0; ni < 4; ++ni)
                    acc[mi][ni] = __builtin_amdgcn_mfma_f32_16x16x32_bf16(
                        af[mi], bfv[ni], acc[mi][ni], 0, 0, 0);
        }
        if (nt < 2) {
            // V epilogue: acc(e,d) -> Vt[d][e] bf16 (transposed scatter)
            #pragma unroll
            for (int mi = 0; mi < 2; ++mi)
                #pragma unroll
                for (int ni = 0; ni < 4; ++ni)
                    #pragma unroll
                    for (int r = 0; r < 4; ++r)
                        Vt[nt * 128 + wn + ni * 16 + lr][wm + mi * 16 + kg * 4 + r] =
                            f2bf(acc[mi][ni][r]);
            // no barrier needed: next reads of Vt are behind later barriers
        } else {
            int st = nt - 2;
            // chunk-local col max over this wave's 32 rows
            float tmax[4];
            #pragma unroll
            for (int ni = 0; ni < 4; ++ni) {
                float m = -1e30f;
                #pragma unroll
                for (int mi = 0; mi < 2; ++mi)
                    #pragma unroll
                    for (int r = 0; r < 4; ++r) m = fmaxf(m, acc[mi][ni][r]);
                m = fmaxf(m, __shfl_xor(m, 16, 64));
                m = fmaxf(m, __shfl_xor(m, 32, 64));
                tmax[ni] = m;
            }
            if (kg == 0) {
                #pragma unroll
                for (int ni = 0; ni < 4; ++ni) smx[w & 1][wn + ni * 16 + lr] = tmax[ni];
            }
            __syncthreads();
            // P = exp(score - m) fp32 -> bf16 (num/den consistent), Pt scatter
            float tsum[4];
            #pragma unroll
            for (int ni = 0; ni < 4; ++ni) {
                int col = wn + ni * 16 + lr;
                float m = fmaxf(smx[0][col], smx[1][col]);
                float sv = 0.f;
                #pragma unroll
                for (int mi = 0; mi < 2; ++mi)
                    #pragma unroll
                    for (int r = 0; r < 4; ++r) {
                        float e_ = __expf(acc[mi][ni][r] - m);
                        unsigned short eb = f2bf(e_);
                        Pt[col][wm + mi * 16 + kg * 4 + r] = eb;
                        sv += bf2f(eb);
                    }
                sv += __shfl_xor(sv, 16, 64);
                sv += __shfl_xor(sv, 32, 64);
                tsum[ni] = sv;
            }
            if (kg == 0) {
                #pragma unroll
                for (int ni = 0; ni < 4; ++ni) ssm[w & 1][wn + ni * 16 + lr] = tsum[ni];
            }
            __syncthreads();                      // Pt + ssm visible
            if (tid < 128) {
                float m = fmaxf(smx[0][tid], smx[1][tid]);
                float sv = ssm[0][tid] + ssm[1][tid];
                mg[(size_t)chunk * H_DIM + st * 128 + tid] = m;
                sg[(size_t)chunk * H_DIM + st * 128 + tid] = sv;
            }
            // 2nd MFMA: wave w handles head h = st*4+w: out[s,d] += P^T @ V
            #pragma unroll
            for (int ms = 0; ms < 2; ++ms)
                #pragma unroll
                for (int nd = 0; nd < 2; ++nd)
                    #pragma unroll
                    for (int kk = 0; kk < 2; ++kk) {
                        bf16x8 pa = *(const bf16x8*)
                            &Pt[w * 32 + ms * 16 + lr][kk * 32 + kg * 8];
                        bf16x8 vb = *(const bf16x8*)
                            &Vt[(st * 4 + w) * 32 + nd * 16 + lr][kk * 32 + kg * 8];
                        acc2[st][ms][nd] = __builtin_amdgcn_mfma_f32_16x16x32_bf16(
                            pa, vb, acc2[st][ms][nd], 0, 0, 0);
                    }
        }
    }
    // store chunk partial: outc[chunk][s][h*32+d] fp32
    #pragma unroll
    for (int st = 0; st < 2; ++st)
        #pragma unroll
        for (int ms = 0; ms < 2; ++ms)
            #pragma unroll
            for (int nd = 0; nd < 2; ++nd)
                #pragma unroll
                for (int r = 0; r < 4; ++r) {
                    int s_ = ms * 16 + kg * 4 + r;
                    int c_ = (st * 4 + w) * 32 + nd * 16 + lr;
                    outc[((size_t)chunk * 32 + s_) * H_DIM + c_] = acc2[st][ms][nd][r];
                }
}

// ---------------- block reduction helper (256 threads = 4 waves) ----------------
__device__ inline float block_sum256(float v, float* red4) {
    for (int o = 32; o > 0; o >>= 1) v += __shfl_xor(v, o, 64);
    int wid = threadIdx.x >> 6;
    if ((threadIdx.x & 63) == 0) red4[wid] = v;
    __syncthreads();
    float r = red4[0] + red4[1] + red4[2] + red4[3];
    __syncthreads();
    return r;
}

// ---------------- K3: flash combine + y = LN(seed + att @ Wo + bo) ----------------
__global__ __launch_bounds__(256) void k_proj_ln(const float* __restrict__ outc,
                                                 const float* __restrict__ mg,
                                                 const float* __restrict__ sg,
                                                 const float* __restrict__ seed,
                                                 const float* __restrict__ Wo,
                                                 const float* __restrict__ bo,
                                                 const float* __restrict__ ln_g,
                                                 const float* __restrict__ ln_b,
                                                 float* __restrict__ Y) {
    int bs0 = blockIdx.x * 4;             // 4 rows, same graph b
    int c = threadIdx.x;
    int b = bs0 >> 5;
    __shared__ float sscale[4][CPG][8];   // exp(m_j - M)/Den per (row, chunk, head)
    __shared__ float arow[4][H_DIM];
    __shared__ float red4[4];
    if (c < 32) {
        int r = c >> 3, hh = c & 7;
        int s_r = (bs0 + r) & 31;
        int sc = hh * 32 + s_r;           // score col for (s,h)
        float mj[CPG];
        float M = -1e30f;
        #pragma unroll
        for (int j = 0; j < CPG; ++j) {
            mj[j] = mg[(size_t)(b * CPG + j) * H_DIM + sc];
            M = fmaxf(M, mj[j]);
        }
        float Den = 0.f;
        #pragma unroll
        for (int j = 0; j < CPG; ++j)
            Den += sg[(size_t)(b * CPG + j) * H_DIM + sc] * __expf(mj[j] - M);
        float inv = 1.f / Den;
        #pragma unroll
        for (int j = 0; j < CPG; ++j)
            sscale[r][j][hh] = __expf(mj[j] - M) * inv;
    }
    __syncthreads();
    int h = c >> 5;
    #pragma unroll
    for (int r = 0; r < 4; ++r) {
        int s_r = (bs0 + r) & 31;
        float a = 0.f;
        #pragma unroll
        for (int j = 0; j < CPG; ++j)
            a = fmaf(outc[((size_t)(b * CPG + j) * 32 + s_r) * H_DIM + c],
                     sscale[r][j][h], a);
        arow[r][c] = a;
    }
    __syncthreads();
    float acc[4];
    float b0 = bo[c];
    #pragma unroll
    for (int r = 0; r < 4; ++r) acc[r] = b0;
    for (int i = 0; i < H_DIM; i += 4) {
        float4 a0 = *(const float4*)&arow[0][i];
        float4 a1 = *(const float4*)&arow[1][i];
        float4 a2 = *(const float4*)&arow[2][i];
        float4 a3 = *(const float4*)&arow[3][i];
        float w0 = Wo[(i + 0) * H_DIM + c], w1 = Wo[(i + 1) * H_DIM + c];
        float w2 = Wo[(i + 2) * H_DIM + c], w3 = Wo[(i + 3) * H_DIM + c];
        acc[0] = fmaf(a0.x, w0, acc[0]); acc[0] = fmaf(a0.y, w1, acc[0]);
        acc[0] = fmaf(a0.z, w2, acc[0]); acc[0] = fmaf(a0.w, w3, acc[0]);
        acc[1] = fmaf(a1.x, w0, acc[1]); acc[1] = fmaf(a1.y, w1, acc[1]);
        acc[1] = fmaf(a1.z, w2, acc[1]); acc[1] = fmaf(a1.w, w3, acc[1]);
        acc[2] = fmaf(a2.x, w0, acc[2]); acc[2] = fmaf(a2.y, w1, acc[2]);
        acc[2] = fmaf(a2.z, w2, acc[2]); acc[2] = fmaf(a2.w, w3, acc[2]);
        acc[3] = fmaf(a3.x, w0, acc[3]); acc[3] = fmaf(a3.y, w1, acc[3]);
        acc[3] = fmaf(a3.z, w2, acc[3]); acc[3] = fmaf(a3.w, w3, acc[3]);
    }
    float g = ln_g[c], be = ln_b[c];
    #pragma unroll
    for (int r = 0; r < 4; ++r) {
        int bs = bs0 + r;
        float y = seed[(bs & 31) * H_DIM + c] + acc[r];
        float mu = block_sum256(y, red4) * (1.f / 256.f);
        float d = y - mu;
        float var = block_sum256(d * d, red4) * (1.f / 256.f);
        Y[(size_t)bs * H_DIM + c] = d * rsqrtf(var + 1e-5f) * g + be;
    }
}

// ---------------- K4: MLP1 partials, W1 read exactly once ----------------
__global__ __launch_bounds__(256) void k_mlp1(const float* __restrict__ Y,
                                              const float* __restrict__ W1,
                                              float* __restrict__ part) {
    int ch = blockIdx.x;          // 128 chunks x 64 rows of W1
    int c = threadIdx.x;
    int i0 = ch * 64;
    __shared__ float fbuf[16][64];
    #pragma unroll
    for (int it = 0; it < 4; ++it) {
        int li = it * 256 + c;
        fbuf[li >> 6][li & 63] = Y[(size_t)(li >> 6) * 8192 + i0 + (li & 63)];
    }
    __syncthreads();
    float acc[16];
    #pragma unroll
    for (int b = 0; b < 16; ++b) acc[b] = 0.f;
    for (int ii = 0; ii < 64; ++ii) {
        float w = W1[(size_t)(i0 + ii) * H_DIM + c];
        #pragma unroll
        for (int b = 0; b < 16; ++b) acc[b] = fmaf(fbuf[b][ii], w, acc[b]);
    }
    #pragma unroll
    for (int b = 0; b < 16; ++b)
        part[((size_t)b * 128 + ch) * H_DIM + c] = acc[b];
}

// ---------------- K5: reduce + SiLU + @W2 + b2 ----------------
__global__ __launch_bounds__(256) void k_mlp2(const float* __restrict__ part,
                                              const float* __restrict__ b1,
                                              const float* __restrict__ W2,
                                              const float* __restrict__ b2,
                                              float* __restrict__ out) {
    int b = blockIdx.x;
    int c = threadIdx.x;
    float s = b1[c];
    const float* pb = &part[(size_t)b * 128 * H_DIM + c];
    #pragma unroll 4
    for (int ch = 0; ch < 128; ++ch) s += pb[(size_t)ch * H_DIM];
    float h1 = s / (1.f + __expf(-s));
    __shared__ float hrow[H_DIM];
    hrow[c] = h1;
    __syncthreads();
    float acc = b2[c];
    for (int j = 0; j < H_DIM; j += 4) {
        float4 hq = *(const float4*)&hrow[j];
        acc = fmaf(hq.x, W2[(j + 0) * H_DIM + c], acc);
        acc = fmaf(hq.y, W2[(j + 1) * H_DIM + c], acc);
        acc = fmaf(hq.z, W2[(j + 2) * H_DIM + c], acc);
        acc = fmaf(hq.w, W2[(j + 3) * H_DIM + c], acc);
    }
    out[(size_t)b * H_DIM + c] = acc;
}

extern "C" void kernel_launch(void* const* d_in, const int* in_sizes, int n_in,
                              void* d_out, int out_size, void* d_ws, size_t ws_size,
                              hipStream_t stream) {
    const float* edge_features = (const float*)d_in[0];
    const float* seed = (const float*)d_in[3];
    const float* Wq   = (const float*)d_in[4];
    const float* Wk   = (const float*)d_in[5];
    const float* Wv   = (const float*)d_in[6];
    const float* Wo   = (const float*)d_in[7];
    const float* bo   = (const float*)d_in[8];
    const float* ln_g = (const float*)d_in[9];
    const float* ln_b = (const float*)d_in[10];
    const float* W1   = (const float*)d_in[11];
    const float* b1   = (const float*)d_in[12];
    const float* W2   = (const float*)d_in[13];
    const float* b2   = (const float*)d_in[14];
    float* out = (float*)d_out;

    // Workspace layout (floats)
    float* ws = (float*)d_ws;
    unsigned short* WcT = (unsigned short*)ws;                    // 512*256 u16 (65536 f)
    float* outc = ws + 65536;                                     // 256*32*256 = 2097152
    float* mg   = outc + 2097152;                                 // 256*256 = 65536
    float* sg   = mg + 65536;                                     // 65536
    float* Y    = sg + 65536;                                     // 131072
    float* part = Y + 131072;                                     // 524288
    // total ~= 2.95M floats ~= 11.8 MB

    k_wc      <<<512, 256, 0, stream>>>(Wv, Wk, Wq, seed, WcT);
    k_attn    <<<NCHUNK, 256, 0, stream>>>(edge_features, WcT, outc, mg, sg);
    k_proj_ln <<<BGRAPHS * S_SEEDS / 4, 256, 0, stream>>>(outc, mg, sg, seed, Wo, bo, ln_g, ln_b, Y);
    k_mlp1    <<<128, 256, 0, stream>>>(Y, W1, part);
    k_mlp2    <<<BGRAPHS, 256, 0, stream>>>(part, b1, W2, b2, out);
}